// Round 1
// baseline (969.759 us; speedup 1.0000x reference)
//
#include <hip/hip_runtime.h>

typedef short bf16x8 __attribute__((ext_vector_type(8)));
typedef float f32x4  __attribute__((ext_vector_type(4)));

__device__ __forceinline__ float bf2f(unsigned short h){
  union { unsigned int u; float f; } c; c.u = ((unsigned int)h) << 16; return c.f;
}
__device__ __forceinline__ unsigned short f2bf(float f){
  union { float f; unsigned int u; } c; c.f = f;
  unsigned int u = c.u;
  return (unsigned short)((u + 0x7fffu + ((u >> 16) & 1u)) >> 16);
}
__device__ __forceinline__ void gload_lds16(const void* g, void* l){
  __builtin_amdgcn_global_load_lds((const __attribute__((address_space(1))) unsigned int*)g,
                                   (__attribute__((address_space(3))) unsigned int*)l, 16, 0, 0);
}
__device__ __forceinline__ float lrelu(float x){ return x >= 0.f ? x : 0.01f * x; }

// ---------------- x (f32) -> bf16 ----------------
__global__ void cvt_f32_bf16(const float* __restrict__ x, unsigned short* __restrict__ o, int n4){
  int i = blockIdx.x * 256 + threadIdx.x;
  if (i >= n4) return;
  float4 v = ((const float4*)x)[i];
  ushort4 r; r.x = f2bf(v.x); r.y = f2bf(v.y); r.z = f2bf(v.z); r.w = f2bf(v.w);
  ((ushort4*)o)[i] = r;
}

// ---------------- W (K x N, f32) -> Wt (N x K, bf16) ----------------
__global__ void wt_kernel(const float* __restrict__ Wm, unsigned short* __restrict__ Wt, int K, int Nf){
  __shared__ float tile[32][33];
  int n0 = blockIdx.x * 32, k0 = blockIdx.y * 32;
  int tx = threadIdx.x, ty = threadIdx.y;
  for (int i = ty; i < 32; i += 8)
    tile[i][tx] = Wm[(size_t)(k0 + i) * Nf + n0 + tx];
  __syncthreads();
  for (int i = ty; i < 32; i += 8)
    Wt[(size_t)(n0 + i) * K + k0 + tx] = f2bf(tile[tx][i]);
}

// ---------------- counting sort of edges by dst ----------------
__global__ void hist_kernel(const int* __restrict__ dst, int* __restrict__ hist, int E){
  int e = blockIdx.x * 256 + threadIdx.x;
  if (e < E) atomicAdd(&hist[dst[e]], 1);
}

__global__ void scan_kernel(int* __restrict__ hist, int* __restrict__ cursor, int n, int total){
  // single block, 1024 threads; in-place exclusive scan of hist -> row_ptr
  __shared__ int partials[1024];
  const int CH = 20;
  int t = threadIdx.x;
  int base = t * CH;
  int local[CH];
  int s = 0;
  for (int i = 0; i < CH; i++){
    int idx = base + i;
    int v = (idx < n) ? hist[idx] : 0;
    local[i] = s; s += v;
  }
  partials[t] = s;
  __syncthreads();
  for (int off = 1; off < 1024; off <<= 1){
    int v = (t >= off) ? partials[t - off] : 0;
    __syncthreads();
    if (t >= off) partials[t] += v;
    __syncthreads();
  }
  int pre = (t == 0) ? 0 : partials[t - 1];
  for (int i = 0; i < CH; i++){
    int idx = base + i;
    if (idx < n){ int v = pre + local[i]; hist[idx] = v; cursor[idx] = v; }
  }
  if (t == 0){ hist[n] = total; }
}

__global__ void scatter_kernel(const int* __restrict__ src, const int* __restrict__ dst,
                               const float* __restrict__ ew, int* __restrict__ cursor,
                               int* __restrict__ so, float* __restrict__ eo, int E){
  int e = blockIdx.x * 256 + threadIdx.x;
  if (e >= E) return;
  int d = dst[e];
  int p = atomicAdd(&cursor[d], 1);
  so[p] = src[e]; eo[p] = ew[e];
}

// ---------------- GEMM: C(bf16 M x Nf) = A(bf16 M x K) * Wt^T (Wt is Nf x K) ----------------
__global__ __launch_bounds__(256) void gemm_bf16(const unsigned short* __restrict__ A,
                                                 const unsigned short* __restrict__ Bt,
                                                 unsigned short* __restrict__ C,
                                                 int Nf, int K){
  __shared__ unsigned short lsA[128 * 64];
  __shared__ unsigned short lsB[128 * 64];
  const int tid = threadIdx.x;
  const int wave = tid >> 6, lane = tid & 63;
  const int wr = wave >> 1, wc = wave & 1;
  const size_t tm = (size_t)blockIdx.x * 128, tn = (size_t)blockIdx.y * 128;

  f32x4 acc[4][4] = {};

  const int lrow = lane >> 3;            // 0..7
  const int lcol = (lane & 7) * 8;       // bf16 elems, 16B chunks
  const unsigned short* Ab = A  + (tm + wave * 32 + lrow) * (size_t)K + lcol;
  const unsigned short* Bb = Bt + (tn + wave * 32 + lrow) * (size_t)K + lcol;
  unsigned short* lA0 = &lsA[(wave * 32) * 64];
  unsigned short* lB0 = &lsB[(wave * 32) * 64];

  for (int k0 = 0; k0 < K; k0 += 64){
    #pragma unroll
    for (int s = 0; s < 4; s++){
      gload_lds16(Ab + (size_t)s * 8 * K + k0, lA0 + s * 8 * 64);
      gload_lds16(Bb + (size_t)s * 8 * K + k0, lB0 + s * 8 * 64);
    }
    __syncthreads();
    #pragma unroll
    for (int kk = 0; kk < 2; kk++){
      bf16x8 af[4], bfr[4];
      #pragma unroll
      for (int m = 0; m < 4; m++)
        af[m] = *(const bf16x8*)&lsA[(wr * 64 + m * 16 + (lane & 15)) * 64 + kk * 32 + (lane >> 4) * 8];
      #pragma unroll
      for (int n = 0; n < 4; n++)
        bfr[n] = *(const bf16x8*)&lsB[(wc * 64 + n * 16 + (lane & 15)) * 64 + kk * 32 + (lane >> 4) * 8];
      #pragma unroll
      for (int m = 0; m < 4; m++)
        #pragma unroll
        for (int n = 0; n < 4; n++)
          acc[m][n] = __builtin_amdgcn_mfma_f32_16x16x32_bf16(af[m], bfr[n], acc[m][n], 0, 0, 0);
    }
    __syncthreads();
  }
  #pragma unroll
  for (int m = 0; m < 4; m++)
    #pragma unroll
    for (int n = 0; n < 4; n++)
      #pragma unroll
      for (int j = 0; j < 4; j++){
        size_t row = tm + wr * 64 + m * 16 + (lane >> 4) * 4 + j;
        size_t col = tn + wc * 64 + n * 16 + (lane & 15);
        C[row * Nf + col] = f2bf(acc[m][n][j]);
      }
}

// ---------------- CSR aggregation: AGG[n][f] = sum_e ew[e] * H[src[e]][f] ----------------
__global__ __launch_bounds__(256) void agg_csr(const unsigned short* __restrict__ H,
                                               const int* __restrict__ rp,
                                               const int* __restrict__ srcs,
                                               const float* __restrict__ ews,
                                               float* __restrict__ AGG, int F){
  int node = blockIdx.x;
  int t = threadIdx.x;
  int e0 = rp[node], e1 = rp[node + 1];
  float a0 = 0.f, a1 = 0.f, a2 = 0.f;
  const int f1 = t + 256, f2 = t + 512;
  for (int e = e0; e < e1; e++){
    int s = srcs[e]; float w = ews[e];
    const unsigned short* hr = H + (size_t)s * F;
    a0 += w * bf2f(hr[t]);
    if (f1 < F) a1 += w * bf2f(hr[f1]);
    if (f2 < F) a2 += w * bf2f(hr[f2]);
  }
  float* orow = AGG + (size_t)node * F;
  orow[t] = a0;
  if (f1 < F) orow[f1] = a1;
  if (f2 < F) orow[f2] = a2;
}

// ---------------- column stats (sum, sumsq) over 20000 rows ----------------
__global__ void stats_kernel(const float* __restrict__ AGG, float* __restrict__ sum,
                             float* __restrict__ sumsq, int F){
  int f = blockIdx.x * 256 + threadIdx.x;
  if (f >= F) return;
  int r0 = blockIdx.y * 500;
  const float* p = AGG + (size_t)r0 * F + f;
  float s = 0.f, q = 0.f;
  for (int r = 0; r < 500; r++){ float v = p[(size_t)r * F]; s += v; q += v * v; }
  atomicAdd(&sum[f], s); atomicAdd(&sumsq[f], q);
}

// ---------------- BN (training stats) + LeakyReLU + cast to bf16 ----------------
__global__ void norm_kernel(const float* __restrict__ AGG, const float* __restrict__ sum,
                            const float* __restrict__ sumsq, const float* __restrict__ gw,
                            const float* __restrict__ bw, unsigned short* __restrict__ OUT, int F){
  int r = blockIdx.x;
  const float inv = 1.0f / 20000.0f;
  for (int f = threadIdx.x; f < F; f += 256){
    float m = sum[f] * inv;
    float v = fmaxf(sumsq[f] * inv - m * m, 0.f);
    float rs = rsqrtf(v + 1e-5f);
    float x = (AGG[(size_t)r * F + f] - m) * rs * gw[f] + bw[f];
    OUT[(size_t)r * F + f] = f2bf(lrelu(x));
  }
}

// ---------------- graph boundaries in sorted batch ----------------
__global__ void bounds_kernel(const int* __restrict__ batch, int* __restrict__ gstart, int n){
  int g = threadIdx.x;
  if (g > 256) return;
  int lo = 0, hi = n;
  while (lo < hi){ int mid = (lo + hi) >> 1; if (batch[mid] < g) lo = mid + 1; else hi = mid; }
  gstart[g] = lo;
}

// ---------------- pooling: pooled[g][f] = sum over node range ----------------
__global__ void pool_kernel(const unsigned short* __restrict__ A1, const int* __restrict__ gstart,
                            float* __restrict__ pooled){
  int g = blockIdx.x, f = threadIdx.x;
  int r0 = gstart[g], r1 = gstart[g + 1];
  float acc = 0.f;
  for (int r = r0; r < r1; r++) acc += bf2f(A1[(size_t)r * 256 + f]);
  pooled[g * 256 + f] = acc;
}

// ---------------- fused FC head: 256->128->64->2 with lrelu ----------------
__global__ void fc_kernel(const float* __restrict__ pooled,
                          const float* __restrict__ Wf1, const float* __restrict__ bf1,
                          const float* __restrict__ Wf2, const float* __restrict__ bf2,
                          const float* __restrict__ Wf3, const float* __restrict__ bf3,
                          float* __restrict__ out){
  int g = blockIdx.x, t = threadIdx.x; // 128 threads
  __shared__ float p0[256], p1[128], p2[64];
  p0[t] = pooled[g * 256 + t];
  p0[t + 128] = pooled[g * 256 + t + 128];
  __syncthreads();
  float a = bf1[t];
  for (int k = 0; k < 256; k++) a += p0[k] * Wf1[k * 128 + t];
  p1[t] = lrelu(a);
  __syncthreads();
  if (t < 64){
    float a2 = bf2[t];
    for (int k = 0; k < 128; k++) a2 += p1[k] * Wf2[k * 64 + t];
    p2[t] = lrelu(a2);
  }
  __syncthreads();
  if (t < 2){
    float a3 = bf3[t];
    for (int k = 0; k < 64; k++) a3 += p2[k] * Wf3[k * 2 + t];
    out[g * 2 + t] = lrelu(a3);
  }
}

extern "C" void kernel_launch(void* const* d_in, const int* in_sizes, int n_in,
                              void* d_out, int out_size, void* d_ws, size_t ws_size,
                              hipStream_t stream){
  const int N = 20000, E = 320000;
  const float* x     = (const float*)d_in[0];
  const int*   ei    = (const int*)d_in[1];
  const float* ew    = (const float*)d_in[2];
  const int*   batch = (const int*)d_in[3];
  const float* W[4]  = {(const float*)d_in[4], (const float*)d_in[8], (const float*)d_in[12], (const float*)d_in[16]};
  const float* gw[4] = {(const float*)d_in[6], (const float*)d_in[10], (const float*)d_in[14], (const float*)d_in[18]};
  const float* bw[4] = {(const float*)d_in[7], (const float*)d_in[11], (const float*)d_in[15], (const float*)d_in[19]};
  const float* Wf1 = (const float*)d_in[20]; const float* bf1 = (const float*)d_in[21];
  const float* Wf2 = (const float*)d_in[22]; const float* bf2 = (const float*)d_in[23];
  const float* Wf3 = (const float*)d_in[24]; const float* bf3 = (const float*)d_in[25];

  const int Kd[4] = {1280, 640, 512, 256};
  const int Nd[4] = {640, 512, 256, 256};

  // workspace carve (XB aliases AGG: XB dead after layer-1 GEMM)
  char* w = (char*)d_ws;
  unsigned short* XB = (unsigned short*)w;
  float* AGG = (float*)w;                 w += 51445760;  // 20096*1280*2
  unsigned short* H  = (unsigned short*)w; w += 25722880; // 20096*640*2
  unsigned short* A1 = (unsigned short*)w; w += 25722880; // 20096*640*2
  unsigned short* WT = (unsigned short*)w; w += 1638400;  // 1280*640*2
  int*   hist   = (int*)w;   w += 80128;  // 20001 ints (becomes row_ptr)
  int*   cursor = (int*)w;   w += 80128;
  int*   srcs   = (int*)w;   w += 1280000;
  float* ews    = (float*)w; w += 1280000;
  float* sum    = (float*)w; w += 2560;
  float* sumsq  = (float*)w; w += 2560;   // adjacent to sum: one memset
  int*   gstart = (int*)w;   w += 1280;
  float* pooled = (float*)w; w += 262144;
  (void)ws_size; (void)n_in; (void)in_sizes; (void)out_size;

  // x -> bf16 (pad rows keep poison: tiny finite values, never consumed)
  cvt_f32_bf16<<<(N * 1280 / 4 + 255) / 256, 256, 0, stream>>>(x, XB, N * 1280 / 4);

  // CSR build: hist -> scan -> scatter
  hipMemsetAsync(hist, 0, 80128, stream);
  hist_kernel<<<E / 256, 256, 0, stream>>>(ei + E, hist, E);
  scan_kernel<<<1, 1024, 0, stream>>>(hist, cursor, N, E);
  scatter_kernel<<<E / 256, 256, 0, stream>>>(ei, ei + E, ew, cursor, srcs, ews, E);

  // graph boundaries
  bounds_kernel<<<1, 320, 0, stream>>>(batch, gstart, N);

  const unsigned short* in = XB;
  for (int l = 0; l < 4; l++){
    int K = Kd[l], Nf = Nd[l];
    wt_kernel<<<dim3(Nf / 32, K / 32), dim3(32, 8), 0, stream>>>(W[l], WT, K, Nf);
    gemm_bf16<<<dim3(157, Nf / 128), 256, 0, stream>>>(in, WT, H, Nf, K);
    agg_csr<<<N, 256, 0, stream>>>(H, hist, srcs, ews, AGG, Nf);
    hipMemsetAsync(sum, 0, 5120, stream);
    stats_kernel<<<dim3((Nf + 255) / 256, 40), 256, 0, stream>>>(AGG, sum, sumsq, Nf);
    norm_kernel<<<N, 256, 0, stream>>>(AGG, sum, sumsq, gw[l], bw[l], A1, Nf);
    in = A1;
  }

  pool_kernel<<<256, 256, 0, stream>>>(A1, gstart, pooled);
  fc_kernel<<<256, 128, 0, stream>>>(pooled, Wf1, bf1, Wf2, bf2, Wf3, bf3, (float*)d_out);
}

// Round 2
// 777.169 us; speedup vs baseline: 1.2478x; 1.2478x over previous
//
#include <hip/hip_runtime.h>

typedef short bf16x8 __attribute__((ext_vector_type(8)));
typedef float f32x4  __attribute__((ext_vector_type(4)));

__device__ __forceinline__ float bf2f(unsigned short h){
  union { unsigned int u; float f; } c; c.u = ((unsigned int)h) << 16; return c.f;
}
__device__ __forceinline__ unsigned short f2bf(float f){
  union { float f; unsigned int u; } c; c.f = f;
  unsigned int u = c.u;
  return (unsigned short)((u + 0x7fffu + ((u >> 16) & 1u)) >> 16);
}
__device__ __forceinline__ void gload_lds16(const void* g, void* l){
  __builtin_amdgcn_global_load_lds((const __attribute__((address_space(1))) unsigned int*)g,
                                   (__attribute__((address_space(3))) unsigned int*)l, 16, 0, 0);
}
__device__ __forceinline__ float lrelu(float x){ return x >= 0.f ? x : 0.01f * x; }

// ---------------- x (f32) -> bf16 ----------------
__global__ void cvt_f32_bf16(const float* __restrict__ x, unsigned short* __restrict__ o, int n4){
  int i = blockIdx.x * 256 + threadIdx.x;
  if (i >= n4) return;
  float4 v = ((const float4*)x)[i];
  ushort4 r; r.x = f2bf(v.x); r.y = f2bf(v.y); r.z = f2bf(v.z); r.w = f2bf(v.w);
  ((ushort4*)o)[i] = r;
}

// ---------------- W (K x N, f32) -> Wt (N x K, bf16) ----------------
__global__ void wt_kernel(const float* __restrict__ Wm, unsigned short* __restrict__ Wt, int K, int Nf){
  __shared__ float tile[32][33];
  int n0 = blockIdx.x * 32, k0 = blockIdx.y * 32;
  int tx = threadIdx.x, ty = threadIdx.y;
  for (int i = ty; i < 32; i += 8)
    tile[i][tx] = Wm[(size_t)(k0 + i) * Nf + n0 + tx];
  __syncthreads();
  for (int i = ty; i < 32; i += 8)
    Wt[(size_t)(n0 + i) * K + k0 + tx] = f2bf(tile[tx][i]);
}

// ---------------- counting sort of edges by dst ----------------
__global__ void hist_kernel(const int* __restrict__ dst, int* __restrict__ hist, int E){
  int e = blockIdx.x * 256 + threadIdx.x;
  if (e < E) atomicAdd(&hist[dst[e]], 1);
}

__global__ void scan_kernel(int* __restrict__ hist, int* __restrict__ cursor, int n, int total){
  __shared__ int partials[1024];
  const int CH = 20;
  int t = threadIdx.x;
  int base = t * CH;
  int local[CH];
  int s = 0;
  for (int i = 0; i < CH; i++){
    int idx = base + i;
    int v = (idx < n) ? hist[idx] : 0;
    local[i] = s; s += v;
  }
  partials[t] = s;
  __syncthreads();
  for (int off = 1; off < 1024; off <<= 1){
    int v = (t >= off) ? partials[t - off] : 0;
    __syncthreads();
    if (t >= off) partials[t] += v;
    __syncthreads();
  }
  int pre = (t == 0) ? 0 : partials[t - 1];
  for (int i = 0; i < CH; i++){
    int idx = base + i;
    if (idx < n){ int v = pre + local[i]; hist[idx] = v; cursor[idx] = v; }
  }
  if (t == 0){ hist[n] = total; }
}

__global__ void scatter_kernel(const int* __restrict__ src, const int* __restrict__ dst,
                               const float* __restrict__ ew, int* __restrict__ cursor,
                               int* __restrict__ so, float* __restrict__ eo, int E){
  int e = blockIdx.x * 256 + threadIdx.x;
  if (e >= E) return;
  int d = dst[e];
  int p = atomicAdd(&cursor[d], 1);
  so[p] = src[e]; eo[p] = ew[e];
}

// ---------------- GEMM: C(bf16 M x Nf) = A(bf16 M x K) * Wt^T (Wt is Nf x K) ----------------
__global__ __launch_bounds__(256) void gemm_bf16(const unsigned short* __restrict__ A,
                                                 const unsigned short* __restrict__ Bt,
                                                 unsigned short* __restrict__ C,
                                                 int Nf, int K){
  __shared__ unsigned short lsA[128 * 64];
  __shared__ unsigned short lsB[128 * 64];
  const int tid = threadIdx.x;
  const int wave = tid >> 6, lane = tid & 63;
  const int wr = wave >> 1, wc = wave & 1;
  const size_t tm = (size_t)blockIdx.x * 128, tn = (size_t)blockIdx.y * 128;

  f32x4 acc[4][4] = {};

  const int lrow = lane >> 3;
  const int lcol = (lane & 7) * 8;
  const unsigned short* Ab = A  + (tm + wave * 32 + lrow) * (size_t)K + lcol;
  const unsigned short* Bb = Bt + (tn + wave * 32 + lrow) * (size_t)K + lcol;
  unsigned short* lA0 = &lsA[(wave * 32) * 64];
  unsigned short* lB0 = &lsB[(wave * 32) * 64];

  for (int k0 = 0; k0 < K; k0 += 64){
    #pragma unroll
    for (int s = 0; s < 4; s++){
      gload_lds16(Ab + (size_t)s * 8 * K + k0, lA0 + s * 8 * 64);
      gload_lds16(Bb + (size_t)s * 8 * K + k0, lB0 + s * 8 * 64);
    }
    __syncthreads();
    #pragma unroll
    for (int kk = 0; kk < 2; kk++){
      bf16x8 af[4], bfr[4];
      #pragma unroll
      for (int m = 0; m < 4; m++)
        af[m] = *(const bf16x8*)&lsA[(wr * 64 + m * 16 + (lane & 15)) * 64 + kk * 32 + (lane >> 4) * 8];
      #pragma unroll
      for (int n = 0; n < 4; n++)
        bfr[n] = *(const bf16x8*)&lsB[(wc * 64 + n * 16 + (lane & 15)) * 64 + kk * 32 + (lane >> 4) * 8];
      #pragma unroll
      for (int m = 0; m < 4; m++)
        #pragma unroll
        for (int n = 0; n < 4; n++)
          acc[m][n] = __builtin_amdgcn_mfma_f32_16x16x32_bf16(af[m], bfr[n], acc[m][n], 0, 0, 0);
    }
    __syncthreads();
  }
  #pragma unroll
  for (int m = 0; m < 4; m++)
    #pragma unroll
    for (int n = 0; n < 4; n++)
      #pragma unroll
      for (int j = 0; j < 4; j++){
        size_t row = tm + wr * 64 + m * 16 + (lane >> 4) * 4 + j;
        size_t col = tn + wc * 64 + n * 16 + (lane & 15);
        C[row * Nf + col] = f2bf(acc[m][n][j]);
      }
}

// ---------------- vectorized CSR aggregation ----------------
// Each block = one node. CH = F/8 chunk lanes (16B bf16x8 loads), G edge-groups.
template<int F, int G>
__global__ __launch_bounds__((F / 8) * G)
void agg_csr_v(const unsigned short* __restrict__ H,
               const int* __restrict__ rp,
               const int* __restrict__ srcs,
               const float* __restrict__ ews,
               float* __restrict__ AGG){
  constexpr int CH = F / 8;
  const int node = blockIdx.x;
  const int t = threadIdx.x;
  const int c = t % CH, g = t / CH;
  const int e0 = rp[node], e1 = rp[node + 1];
  const size_t coff = (size_t)c * 8;

  float acc[8] = {0.f,0.f,0.f,0.f,0.f,0.f,0.f,0.f};
  int e = e0 + g;
  for (; e + G < e1; e += 2 * G){
    int s0 = srcs[e];     float w0 = ews[e];
    int s1 = srcs[e + G]; float w1 = ews[e + G];
    bf16x8 v0 = *(const bf16x8*)&H[(size_t)s0 * F + coff];
    bf16x8 v1 = *(const bf16x8*)&H[(size_t)s1 * F + coff];
    #pragma unroll
    for (int j = 0; j < 8; j++) acc[j] += w0 * bf2f((unsigned short)v0[j]);
    #pragma unroll
    for (int j = 0; j < 8; j++) acc[j] += w1 * bf2f((unsigned short)v1[j]);
  }
  if (e < e1){
    int s0 = srcs[e]; float w0 = ews[e];
    bf16x8 v0 = *(const bf16x8*)&H[(size_t)s0 * F + coff];
    #pragma unroll
    for (int j = 0; j < 8; j++) acc[j] += w0 * bf2f((unsigned short)v0[j]);
  }

  __shared__ float red[G][F];
  if (g > 0){
    #pragma unroll
    for (int j = 0; j < 8; j++) red[g][c * 8 + j] = acc[j];
  }
  __syncthreads();
  if (g == 0){
    #pragma unroll
    for (int gg = 1; gg < G; gg++)
      #pragma unroll
      for (int j = 0; j < 8; j++) acc[j] += red[gg][c * 8 + j];
    float* orow = AGG + (size_t)node * F + coff;
    #pragma unroll
    for (int j = 0; j < 8; j++) orow[j] = acc[j];
  }
}

// ---------------- column stats (sum, sumsq) over 20000 rows ----------------
__global__ void stats_kernel(const float* __restrict__ AGG, float* __restrict__ sum,
                             float* __restrict__ sumsq, int F){
  int f = blockIdx.x * 256 + threadIdx.x;
  if (f >= F) return;
  int r0 = blockIdx.y * 500;
  const float* p = AGG + (size_t)r0 * F + f;
  float s = 0.f, q = 0.f;
  for (int r = 0; r < 500; r++){ float v = p[(size_t)r * F]; s += v; q += v * v; }
  atomicAdd(&sum[f], s); atomicAdd(&sumsq[f], q);
}

// ---------------- BN (training stats) + LeakyReLU + cast to bf16 ----------------
__global__ void norm_kernel(const float* __restrict__ AGG, const float* __restrict__ sum,
                            const float* __restrict__ sumsq, const float* __restrict__ gw,
                            const float* __restrict__ bw, unsigned short* __restrict__ OUT, int F){
  int r = blockIdx.x;
  const float inv = 1.0f / 20000.0f;
  for (int f = threadIdx.x; f < F; f += 256){
    float m = sum[f] * inv;
    float v = fmaxf(sumsq[f] * inv - m * m, 0.f);
    float rs = rsqrtf(v + 1e-5f);
    float x = (AGG[(size_t)r * F + f] - m) * rs * gw[f] + bw[f];
    OUT[(size_t)r * F + f] = f2bf(lrelu(x));
  }
}

// ---------------- graph boundaries in sorted batch ----------------
__global__ void bounds_kernel(const int* __restrict__ batch, int* __restrict__ gstart, int n){
  int g = threadIdx.x;
  if (g > 256) return;
  int lo = 0, hi = n;
  while (lo < hi){ int mid = (lo + hi) >> 1; if (batch[mid] < g) lo = mid + 1; else hi = mid; }
  gstart[g] = lo;
}

// ---------------- pooling (vectorized): pooled[g][f] = sum over node range ----------------
__global__ __launch_bounds__(256) void pool_kernel_v(const unsigned short* __restrict__ A1,
                                                     const int* __restrict__ gstart,
                                                     float* __restrict__ pooled){
  int gph = blockIdx.x;
  int t = threadIdx.x;
  int c = t & 31, g = t >> 5;            // 32 chunks x 8 row-groups
  int r0 = gstart[gph], r1 = gstart[gph + 1];
  float acc[8] = {0.f,0.f,0.f,0.f,0.f,0.f,0.f,0.f};
  for (int r = r0 + g; r < r1; r += 8){
    bf16x8 v = *(const bf16x8*)&A1[(size_t)r * 256 + c * 8];
    #pragma unroll
    for (int j = 0; j < 8; j++) acc[j] += bf2f((unsigned short)v[j]);
  }
  __shared__ float red[8][256];
  if (g > 0){
    #pragma unroll
    for (int j = 0; j < 8; j++) red[g][c * 8 + j] = acc[j];
  }
  __syncthreads();
  if (g == 0){
    #pragma unroll
    for (int gg = 1; gg < 8; gg++)
      #pragma unroll
      for (int j = 0; j < 8; j++) acc[j] += red[gg][c * 8 + j];
    #pragma unroll
    for (int j = 0; j < 8; j++) pooled[gph * 256 + c * 8 + j] = acc[j];
  }
}

// ---------------- fused FC head: 256->128->64->2 with lrelu ----------------
__global__ void fc_kernel(const float* __restrict__ pooled,
                          const float* __restrict__ Wf1, const float* __restrict__ bf1,
                          const float* __restrict__ Wf2, const float* __restrict__ bf2,
                          const float* __restrict__ Wf3, const float* __restrict__ bf3,
                          float* __restrict__ out){
  int g = blockIdx.x, t = threadIdx.x; // 128 threads
  __shared__ float p0[256], p1[128], p2[64];
  p0[t] = pooled[g * 256 + t];
  p0[t + 128] = pooled[g * 256 + t + 128];
  __syncthreads();
  float a = bf1[t];
  for (int k = 0; k < 256; k++) a += p0[k] * Wf1[k * 128 + t];
  p1[t] = lrelu(a);
  __syncthreads();
  if (t < 64){
    float a2 = bf2[t];
    for (int k = 0; k < 128; k++) a2 += p1[k] * Wf2[k * 64 + t];
    p2[t] = lrelu(a2);
  }
  __syncthreads();
  if (t < 2){
    float a3 = bf3[t];
    for (int k = 0; k < 64; k++) a3 += p2[k] * Wf3[k * 2 + t];
    out[g * 2 + t] = lrelu(a3);
  }
}

extern "C" void kernel_launch(void* const* d_in, const int* in_sizes, int n_in,
                              void* d_out, int out_size, void* d_ws, size_t ws_size,
                              hipStream_t stream){
  const int N = 20000, E = 320000;
  const float* x     = (const float*)d_in[0];
  const int*   ei    = (const int*)d_in[1];
  const float* ew    = (const float*)d_in[2];
  const int*   batch = (const int*)d_in[3];
  const float* W[4]  = {(const float*)d_in[4], (const float*)d_in[8], (const float*)d_in[12], (const float*)d_in[16]};
  const float* gw[4] = {(const float*)d_in[6], (const float*)d_in[10], (const float*)d_in[14], (const float*)d_in[18]};
  const float* bw[4] = {(const float*)d_in[7], (const float*)d_in[11], (const float*)d_in[15], (const float*)d_in[19]};
  const float* Wf1 = (const float*)d_in[20]; const float* bf1 = (const float*)d_in[21];
  const float* Wf2 = (const float*)d_in[22]; const float* bf2 = (const float*)d_in[23];
  const float* Wf3 = (const float*)d_in[24]; const float* bf3 = (const float*)d_in[25];

  const int Kd[4] = {1280, 640, 512, 256};
  const int Nd[4] = {640, 512, 256, 256};

  // workspace carve (XB aliases AGG: XB dead after layer-1 GEMM)
  char* w = (char*)d_ws;
  unsigned short* XB = (unsigned short*)w;
  float* AGG = (float*)w;                 w += 51445760;  // 20096*1280*2
  unsigned short* H  = (unsigned short*)w; w += 25722880; // 20096*640*2
  unsigned short* A1 = (unsigned short*)w; w += 25722880; // 20096*640*2
  unsigned short* WT = (unsigned short*)w; w += 1638400;  // 1280*640*2
  int*   hist   = (int*)w;   w += 80128;  // 20001 ints (becomes row_ptr)
  int*   cursor = (int*)w;   w += 80128;
  int*   srcs   = (int*)w;   w += 1280000;
  float* ews    = (float*)w; w += 1280000;
  float* sum    = (float*)w; w += 2560;
  float* sumsq  = (float*)w; w += 2560;   // adjacent to sum: one memset
  int*   gstart = (int*)w;   w += 1280;
  float* pooled = (float*)w; w += 262144;
  (void)ws_size; (void)n_in; (void)in_sizes; (void)out_size;

  cvt_f32_bf16<<<(N * 1280 / 4 + 255) / 256, 256, 0, stream>>>(x, XB, N * 1280 / 4);

  hipMemsetAsync(hist, 0, 80128, stream);
  hist_kernel<<<E / 256, 256, 0, stream>>>(ei + E, hist, E);
  scan_kernel<<<1, 1024, 0, stream>>>(hist, cursor, N, E);
  scatter_kernel<<<E / 256, 256, 0, stream>>>(ei, ei + E, ew, cursor, srcs, ews, E);

  bounds_kernel<<<1, 320, 0, stream>>>(batch, gstart, N);

  const unsigned short* in = XB;
  for (int l = 0; l < 4; l++){
    int K = Kd[l], Nf = Nd[l];
    wt_kernel<<<dim3(Nf / 32, K / 32), dim3(32, 8), 0, stream>>>(W[l], WT, K, Nf);
    gemm_bf16<<<dim3(157, Nf / 128), 256, 0, stream>>>(in, WT, H, Nf, K);
    if (Nf == 640)      agg_csr_v<640, 4><<<N, 320, 0, stream>>>(H, hist, srcs, ews, AGG);
    else if (Nf == 512) agg_csr_v<512, 4><<<N, 256, 0, stream>>>(H, hist, srcs, ews, AGG);
    else                agg_csr_v<256, 8><<<N, 256, 0, stream>>>(H, hist, srcs, ews, AGG);
    hipMemsetAsync(sum, 0, 5120, stream);
    stats_kernel<<<dim3((Nf + 255) / 256, 40), 256, 0, stream>>>(AGG, sum, sumsq, Nf);
    norm_kernel<<<N, 256, 0, stream>>>(AGG, sum, sumsq, gw[l], bw[l], A1, Nf);
    in = A1;
  }

  pool_kernel_v<<<256, 256, 0, stream>>>(A1, gstart, pooled);
  fc_kernel<<<256, 128, 0, stream>>>(pooled, Wf1, bf1, Wf2, bf2, Wf3, bf3, (float*)d_out);
}